// Round 1
// baseline (247.298 us; speedup 1.0000x reference)
//
#include <hip/hip_runtime.h>
#include <stdint.h>

#define NE 8
#define ND 512
#define NH1 512
#define NH2 256
#define NY 256
#define NB 8192
#define BM 128
#define BK 32
#define MAXT (NB/BM + NE - 1)   /* 71 */
#define PADROWS (NB + BM)       /* 8320 */

typedef float f32x4 __attribute__((ext_vector_type(4)));
typedef __bf16 bf16x8 __attribute__((ext_vector_type(8)));
typedef unsigned short u16x8 __attribute__((ext_vector_type(8)));

__device__ __forceinline__ unsigned short f2bf(float f) {
  unsigned int u = __float_as_uint(f);
  u += 0x7fffu + ((u >> 16) & 1u);   // round-to-nearest-even
  return (unsigned short)(u >> 16);
}

__device__ __forceinline__ void async_cp16(const void* g, void* l) {
  __builtin_amdgcn_global_load_lds((const __attribute__((address_space(1))) void*)g,
                                   (__attribute__((address_space(3))) void*)l,
                                   16, 0, 0);
}

// meta (ints): [0..7] counts, [8..15] offs, [16..23] cursors, [24] ntiles, [32..127] tile table

__global__ void zero_k(int* meta) {
  if (threadIdx.x < 32) meta[threadIdx.x] = 0;
}

__global__ void hist_k(const int* __restrict__ gate, int* __restrict__ meta) {
  __shared__ int lc[NE];
  int tid = threadIdx.x;
  if (tid < NE) lc[tid] = 0;
  __syncthreads();
  int g = gate[blockIdx.x * 256 + tid];
  g = g < 0 ? 0 : (g > NE - 1 ? NE - 1 : g);
  atomicAdd(&lc[g], 1);
  __syncthreads();
  if (tid < NE) atomicAdd(&meta[tid], lc[tid]);
}

__global__ void scan_k(int* meta) {
  if (threadIdx.x == 0) {
    int off = 0, t = 0;
    for (int e = 0; e < NE; e++) {
      int c = meta[e];
      meta[8 + e] = off;
      meta[16 + e] = off;
      int ntl = (c + BM - 1) / BM;
      for (int i = 0; i < ntl; i++) meta[32 + t++] = (e << 16) | i;
      off += c;
    }
    meta[24] = t;
  }
}

// one wave per row: assign sorted slot, gather h row fp32 -> bf16
__global__ void gather_k(const float* __restrict__ h, const int* __restrict__ gate,
                         int* __restrict__ meta, int* __restrict__ perm,
                         unsigned short* __restrict__ hs) {
  int row  = blockIdx.x * 4 + (threadIdx.x >> 6);
  int lane = threadIdx.x & 63;
  int slot = 0;
  if (lane == 0) {
    int g = gate[row];
    g = g < 0 ? 0 : (g > NE - 1 ? NE - 1 : g);
    slot = atomicAdd(&meta[16 + g], 1);
    perm[slot] = row;
  }
  slot = __shfl(slot, 0, 64);
  const float4* src = (const float4*)(h + (size_t)row * ND) + lane * 2;
  float4 v0 = src[0], v1 = src[1];
  union { u16x8 v; unsigned short u[8]; } pk;
  pk.u[0] = f2bf(v0.x); pk.u[1] = f2bf(v0.y); pk.u[2] = f2bf(v0.z); pk.u[3] = f2bf(v0.w);
  pk.u[4] = f2bf(v1.x); pk.u[5] = f2bf(v1.y); pk.u[6] = f2bf(v1.z); pk.u[7] = f2bf(v1.w);
  *(u16x8*)(hs + (size_t)slot * ND + lane * 8) = pk.v;
}

// W [G][K][N] fp32  ->  Wt [G][N][K] bf16 (LDS-tiled transpose)
__global__ void wtrans_k(const float* __restrict__ W, unsigned short* __restrict__ Wt,
                         int K, int N) {
  __shared__ float t[32][33];
  int g  = blockIdx.z;
  int n0 = blockIdx.x * 32, k0 = blockIdx.y * 32;
  int tx = threadIdx.x, ty = threadIdx.y;
  const float* src = W + (size_t)g * K * N;
  #pragma unroll
  for (int r = 0; r < 32; r += 8)
    t[ty + r][tx] = src[(size_t)(k0 + ty + r) * N + n0 + tx];
  __syncthreads();
  unsigned short* dst = Wt + (size_t)g * N * K;
  #pragma unroll
  for (int r = 0; r < 32; r += 8)
    dst[(size_t)(n0 + ty + r) * K + k0 + tx] = f2bf(t[tx][ty + r]);
}

// Grouped GEMM over expert-sorted rows. A [rows][K] bf16, Bt [E][N][K] bf16.
// 256 thr = 4 waves (2x2), wave tile 64 x (BN/2), 16x16x32 bf16 MFMA.
template<int BN, int K, int N, bool LEAKY, bool SCATTER>
__global__ __launch_bounds__(256)
void gemm_k(const unsigned short* __restrict__ A,
            const unsigned short* __restrict__ Bt,
            const float* __restrict__ bias,
            const int* __restrict__ meta,
            const int* __restrict__ perm,
            unsigned short* __restrict__ Obf,
            float* __restrict__ Ofp)
{
  constexpr int WN = BN / 2;
  constexpr int FN = WN / 16;
  constexpr int CA = BM * BK * 2 / 1024;   // A chunks of 1024B
  constexpr int CB = BN * BK * 2 / 1024;
  constexpr int CT = CA + CB;

  __shared__ unsigned short As[BM * BK];
  __shared__ unsigned short Bs[BN * BK];

  if ((int)blockIdx.y >= meta[24]) return;
  int ent  = meta[32 + blockIdx.y];
  int e    = ent >> 16;
  int trow = ent & 0xffff;
  int cnt  = meta[e];
  int off  = meta[8 + e];
  int row0 = trow * BM;

  const unsigned short* Ae = A + (size_t)(off + row0) * K;
  const unsigned short* Be = Bt + ((size_t)e * N + (size_t)blockIdx.x * BN) * K;

  int tid  = threadIdx.x;
  int wave = tid >> 6, lane = tid & 63;
  int wx = wave & 1, wy = wave >> 1;
  int lm = lane & 15, quad = lane >> 4;
  int srow = lane >> 2;          // row within 16-row staging chunk
  int scol = (lane & 3) * 8;     // bf16-element offset within row

  f32x4 acc[4][FN];
  f32x4 zero = {0.f, 0.f, 0.f, 0.f};
  #pragma unroll
  for (int mi = 0; mi < 4; mi++)
    #pragma unroll
    for (int ni = 0; ni < FN; ni++)
      acc[mi][ni] = zero;

  for (int k0 = 0; k0 < K; k0 += BK) {
    for (int c = wave; c < CT; c += 4) {
      if (c < CA)
        async_cp16(Ae + (size_t)(c * 16 + srow) * K + k0 + scol, &As[c * 512]);
      else
        async_cp16(Be + (size_t)((c - CA) * 16 + srow) * K + k0 + scol, &Bs[(c - CA) * 512]);
    }
    __syncthreads();
    bf16x8 af[4], bfr[FN];
    #pragma unroll
    for (int mi = 0; mi < 4; mi++)
      af[mi] = *reinterpret_cast<const bf16x8*>(&As[(wy * 64 + mi * 16 + lm) * BK + quad * 8]);
    #pragma unroll
    for (int ni = 0; ni < FN; ni++)
      bfr[ni] = *reinterpret_cast<const bf16x8*>(&Bs[(wx * WN + ni * 16 + lm) * BK + quad * 8]);
    #pragma unroll
    for (int mi = 0; mi < 4; mi++)
      #pragma unroll
      for (int ni = 0; ni < FN; ni++)
        acc[mi][ni] = __builtin_amdgcn_mfma_f32_16x16x32_bf16(af[mi], bfr[ni], acc[mi][ni], 0, 0, 0);
    __syncthreads();
  }

  #pragma unroll
  for (int mi = 0; mi < 4; mi++) {
    #pragma unroll
    for (int ni = 0; ni < FN; ni++) {
      int col = blockIdx.x * BN + wx * WN + ni * 16 + lm;
      float bv = bias[e * N + col];
      #pragma unroll
      for (int r = 0; r < 4; r++) {
        int ml   = wy * 64 + mi * 16 + quad * 4 + r;  // C/D: row=quad*4+reg, col=lane&15
        int grow = row0 + ml;
        if (grow < cnt) {
          float v = acc[mi][ni][r] + bv;
          if (LEAKY) v = (v > 0.f) ? v : 0.2f * v;
          int s = off + grow;
          if (SCATTER)
            Ofp[(size_t)perm[s] * N + col] = v;
          else
            Obf[(size_t)s * N + col] = f2bf(v);
        }
      }
    }
  }
}

extern "C" void kernel_launch(void* const* d_in, const int* in_sizes, int n_in,
                              void* d_out, int out_size, void* d_ws, size_t ws_size,
                              hipStream_t stream) {
  (void)in_sizes; (void)n_in; (void)out_size; (void)ws_size;
  const float* h  = (const float*)d_in[0];
  const int* gate = (const int*)d_in[1];
  const float* W1 = (const float*)d_in[2];
  const float* b1 = (const float*)d_in[3];
  const float* W2 = (const float*)d_in[4];
  const float* b2 = (const float*)d_in[5];
  const float* W3 = (const float*)d_in[6];
  const float* b3 = (const float*)d_in[7];
  float* out = (float*)d_out;

  char* ws = (char*)d_ws;
  int* meta = (int*)ws;                               // 4096 B
  int* perm = (int*)(ws + 4096);                      // 32 KB
  unsigned short* hs  = (unsigned short*)(ws + 4096 + 32768);
  unsigned short* a1s = hs  + (size_t)PADROWS * ND;
  unsigned short* a2s = a1s + (size_t)PADROWS * NH1;
  unsigned short* w1t = a2s + (size_t)PADROWS * NH2;
  unsigned short* w2t = w1t + (size_t)NE * ND * NH1;
  unsigned short* w3t = w2t + (size_t)NE * NH1 * NH2;
  // total ~28.7 MB of d_ws

  zero_k<<<1, 64, 0, stream>>>(meta);
  hist_k<<<NB / 256, 256, 0, stream>>>(gate, meta);
  scan_k<<<1, 1, 0, stream>>>(meta);
  gather_k<<<NB / 4, 256, 0, stream>>>(h, gate, meta, perm, hs);
  wtrans_k<<<dim3(NH1 / 32, ND / 32, NE), dim3(32, 8), 0, stream>>>(W1, w1t, ND, NH1);
  wtrans_k<<<dim3(NH2 / 32, NH1 / 32, NE), dim3(32, 8), 0, stream>>>(W2, w2t, NH1, NH2);
  wtrans_k<<<dim3(NY / 32, NH2 / 32, NE), dim3(32, 8), 0, stream>>>(W3, w3t, NH2, NY);

  gemm_k<64, ND, NH1, true, false><<<dim3(NH1 / 64, MAXT), 256, 0, stream>>>(
      hs, w1t, b1, meta, perm, a1s, (float*)nullptr);
  gemm_k<64, NH1, NH2, true, false><<<dim3(NH2 / 64, MAXT), 256, 0, stream>>>(
      a1s, w2t, b2, meta, perm, a2s, (float*)nullptr);
  gemm_k<64, NH2, NY, false, true><<<dim3(NY / 64, MAXT), 256, 0, stream>>>(
      a2s, w3t, b3, meta, perm, (unsigned short*)nullptr, out);
}

// Round 2
// 153.013 us; speedup vs baseline: 1.6162x; 1.6162x over previous
//
#include <hip/hip_runtime.h>
#include <stdint.h>

#define NE 8
#define ND 512
#define NH1 512
#define NH2 256
#define NY 256
#define NB 8192
#define BM 128
#define BK 32
#define MAXT (NB/BM + NE - 1)   /* 71 */
#define PADROWS (NB + BM)       /* 8320 */

typedef float f32x4 __attribute__((ext_vector_type(4)));
typedef __bf16 bf16x8 __attribute__((ext_vector_type(8)));
typedef unsigned short u16x8 __attribute__((ext_vector_type(8)));

__device__ __forceinline__ unsigned short f2bf(float f) {
  unsigned int u = __float_as_uint(f);
  u += 0x7fffu + ((u >> 16) & 1u);   // round-to-nearest-even
  return (unsigned short)(u >> 16);
}

__device__ __forceinline__ void async_cp16(const void* g, void* l) {
  __builtin_amdgcn_global_load_lds((const __attribute__((address_space(1))) void*)g,
                                   (__attribute__((address_space(3))) void*)l,
                                   16, 0, 0);
}

__device__ __forceinline__ int clampe(int g) {
  return g < 0 ? 0 : (g > NE - 1 ? NE - 1 : g);
}

// meta (ints): [0..7] counts, [8..15] offs, [24] ntiles, [32..127] tile table,
//              [128..383] blockhist[b][e], [512..767] base[b][e]

// 32 blocks x 256 thr: per-block expert histogram + within-block rank (LDS atomics only)
__global__ void hist_rank_k(const int* __restrict__ gate, int* __restrict__ meta,
                            int* __restrict__ rank) {
  __shared__ int lc[NE];
  int tid = threadIdx.x;
  if (tid < NE) lc[tid] = 0;
  __syncthreads();
  int row = blockIdx.x * 256 + tid;
  int g = clampe(gate[row]);
  rank[row] = atomicAdd(&lc[g], 1);
  __syncthreads();
  if (tid < NE) meta[128 + blockIdx.x * NE + tid] = lc[tid];
}

// 1 block x 256 thr: per-expert scan over blocks -> base[b][e], offs, tile table
__global__ void scan_k(int* __restrict__ meta) {
  __shared__ int hist[256];
  __shared__ int basel[256];
  __shared__ int cnt[NE];
  int tid = threadIdx.x;
  hist[tid] = meta[128 + tid];            // [b][e] layout: b*8+e
  __syncthreads();
  if (tid < NE) {
    int run = 0;
    for (int b = 0; b < 32; b++) {
      basel[b * NE + tid] = run;
      run += hist[b * NE + tid];
    }
    cnt[tid] = run;
  }
  __syncthreads();
  __shared__ int offs[NE];
  if (tid == 0) {
    int off = 0, t = 0;
    for (int e = 0; e < NE; e++) {
      int c = cnt[e];
      meta[e] = c;
      meta[8 + e] = off;
      offs[e] = off;
      int ntl = (c + BM - 1) / BM;
      for (int i = 0; i < ntl; i++) meta[32 + t++] = (e << 16) | i;
      off += c;
    }
    meta[24] = t;
  }
  __syncthreads();
  // base[b][e] = offs[e] + prefix_over_blocks
  meta[512 + tid] = offs[tid & (NE - 1)] + basel[tid];
}

// wave per row: slot = base[row>>8][g] + rank; gather h row fp32 -> bf16 sorted
__global__ void copy_k(const float* __restrict__ h, const int* __restrict__ gate,
                       const int* __restrict__ rank, const int* __restrict__ meta,
                       int* __restrict__ perm, unsigned short* __restrict__ hs) {
  int row  = blockIdx.x * 4 + (threadIdx.x >> 6);
  int lane = threadIdx.x & 63;
  int g = clampe(gate[row]);
  int slot = meta[512 + (row >> 8) * NE + g] + rank[row];
  if (lane == 0) perm[slot] = row;
  const float4* src = (const float4*)(h + (size_t)row * ND) + lane * 2;
  float4 v0 = src[0], v1 = src[1];
  union { u16x8 v; unsigned short u[8]; } pk;
  pk.u[0] = f2bf(v0.x); pk.u[1] = f2bf(v0.y); pk.u[2] = f2bf(v0.z); pk.u[3] = f2bf(v0.w);
  pk.u[4] = f2bf(v1.x); pk.u[5] = f2bf(v1.y); pk.u[6] = f2bf(v1.z); pk.u[7] = f2bf(v1.w);
  *(u16x8*)(hs + (size_t)slot * ND + lane * 8) = pk.v;
}

// W [G][K][N] fp32  ->  Wt [G][N][K] bf16 (LDS-tiled transpose)
__global__ void wtrans_k(const float* __restrict__ W, unsigned short* __restrict__ Wt,
                         int K, int N) {
  __shared__ float t[32][33];
  int g  = blockIdx.z;
  int n0 = blockIdx.x * 32, k0 = blockIdx.y * 32;
  int tx = threadIdx.x, ty = threadIdx.y;
  const float* src = W + (size_t)g * K * N;
  #pragma unroll
  for (int r = 0; r < 32; r += 8)
    t[ty + r][tx] = src[(size_t)(k0 + ty + r) * N + n0 + tx];
  __syncthreads();
  unsigned short* dst = Wt + (size_t)g * N * K;
  #pragma unroll
  for (int r = 0; r < 32; r += 8)
    dst[(size_t)(n0 + ty + r) * K + k0 + tx] = f2bf(t[tx][ty + r]);
}

// Grouped GEMM over expert-sorted rows. A [rows][K] bf16, Bt [E][N][K] bf16.
// 256 thr = 4 waves (2x2), wave tile 64 x (BN/2), 16x16x32 bf16 MFMA.
template<int BN, int K, int N, bool LEAKY, bool SCATTER>
__global__ __launch_bounds__(256)
void gemm_k(const unsigned short* __restrict__ A,
            const unsigned short* __restrict__ Bt,
            const float* __restrict__ bias,
            const int* __restrict__ meta,
            const int* __restrict__ perm,
            unsigned short* __restrict__ Obf,
            float* __restrict__ Ofp)
{
  constexpr int WN = BN / 2;
  constexpr int FN = WN / 16;
  constexpr int CA = BM * BK * 2 / 1024;   // A chunks of 1024B
  constexpr int CB = BN * BK * 2 / 1024;
  constexpr int CT = CA + CB;

  __shared__ unsigned short As[BM * BK];
  __shared__ unsigned short Bs[BN * BK];

  if ((int)blockIdx.y >= meta[24]) return;
  int ent  = meta[32 + blockIdx.y];
  int e    = ent >> 16;
  int trow = ent & 0xffff;
  int cnt  = meta[e];
  int off  = meta[8 + e];
  int row0 = trow * BM;

  const unsigned short* Ae = A + (size_t)(off + row0) * K;
  const unsigned short* Be = Bt + ((size_t)e * N + (size_t)blockIdx.x * BN) * K;

  int tid  = threadIdx.x;
  int wave = tid >> 6, lane = tid & 63;
  int wx = wave & 1, wy = wave >> 1;
  int lm = lane & 15, quad = lane >> 4;
  int srow = lane >> 2;          // row within 16-row staging chunk
  int scol = (lane & 3) * 8;     // bf16-element offset within row

  f32x4 acc[4][FN];
  f32x4 zero = {0.f, 0.f, 0.f, 0.f};
  #pragma unroll
  for (int mi = 0; mi < 4; mi++)
    #pragma unroll
    for (int ni = 0; ni < FN; ni++)
      acc[mi][ni] = zero;

  for (int k0 = 0; k0 < K; k0 += BK) {
    for (int c = wave; c < CT; c += 4) {
      if (c < CA)
        async_cp16(Ae + (size_t)(c * 16 + srow) * K + k0 + scol, &As[c * 512]);
      else
        async_cp16(Be + (size_t)((c - CA) * 16 + srow) * K + k0 + scol, &Bs[(c - CA) * 512]);
    }
    __syncthreads();
    bf16x8 af[4], bfr[FN];
    #pragma unroll
    for (int mi = 0; mi < 4; mi++)
      af[mi] = *reinterpret_cast<const bf16x8*>(&As[(wy * 64 + mi * 16 + lm) * BK + quad * 8]);
    #pragma unroll
    for (int ni = 0; ni < FN; ni++)
      bfr[ni] = *reinterpret_cast<const bf16x8*>(&Bs[(wx * WN + ni * 16 + lm) * BK + quad * 8]);
    #pragma unroll
    for (int mi = 0; mi < 4; mi++)
      #pragma unroll
      for (int ni = 0; ni < FN; ni++)
        acc[mi][ni] = __builtin_amdgcn_mfma_f32_16x16x32_bf16(af[mi], bfr[ni], acc[mi][ni], 0, 0, 0);
    __syncthreads();
  }

  #pragma unroll
  for (int mi = 0; mi < 4; mi++) {
    #pragma unroll
    for (int ni = 0; ni < FN; ni++) {
      int col = blockIdx.x * BN + wx * WN + ni * 16 + lm;
      float bv = bias[e * N + col];
      #pragma unroll
      for (int r = 0; r < 4; r++) {
        int ml   = wy * 64 + mi * 16 + quad * 4 + r;  // C/D: row=quad*4+reg, col=lane&15
        int grow = row0 + ml;
        if (grow < cnt) {
          float v = acc[mi][ni][r] + bv;
          if (LEAKY) v = (v > 0.f) ? v : 0.2f * v;
          int s = off + grow;
          if (SCATTER)
            Ofp[(size_t)perm[s] * N + col] = v;
          else
            Obf[(size_t)s * N + col] = f2bf(v);
        }
      }
    }
  }
}

extern "C" void kernel_launch(void* const* d_in, const int* in_sizes, int n_in,
                              void* d_out, int out_size, void* d_ws, size_t ws_size,
                              hipStream_t stream) {
  (void)in_sizes; (void)n_in; (void)out_size; (void)ws_size;
  const float* h  = (const float*)d_in[0];
  const int* gate = (const int*)d_in[1];
  const float* W1 = (const float*)d_in[2];
  const float* b1 = (const float*)d_in[3];
  const float* W2 = (const float*)d_in[4];
  const float* b2 = (const float*)d_in[5];
  const float* W3 = (const float*)d_in[6];
  const float* b3 = (const float*)d_in[7];
  float* out = (float*)d_out;

  char* ws = (char*)d_ws;
  int* meta = (int*)ws;                               // 4096 B
  int* rank = (int*)(ws + 4096);                      // 32 KB
  int* perm = (int*)(ws + 4096 + 32768);              // 32 KB
  unsigned short* hs  = (unsigned short*)(ws + 4096 + 65536);
  unsigned short* a1s = hs  + (size_t)PADROWS * ND;
  unsigned short* a2s = a1s + (size_t)PADROWS * NH1;
  unsigned short* w1t = a2s + (size_t)PADROWS * NH2;
  unsigned short* w2t = w1t + (size_t)NE * ND * NH1;
  unsigned short* w3t = w2t + (size_t)NE * NH1 * NH2;
  // total ~28.8 MB of d_ws

  hist_rank_k<<<NB / 256, 256, 0, stream>>>(gate, meta, rank);
  scan_k<<<1, 256, 0, stream>>>(meta);
  copy_k<<<NB / 4, 256, 0, stream>>>(h, gate, rank, meta, perm, hs);
  wtrans_k<<<dim3(NH1 / 32, ND / 32, NE), dim3(32, 8), 0, stream>>>(W1, w1t, ND, NH1);
  wtrans_k<<<dim3(NH2 / 32, NH1 / 32, NE), dim3(32, 8), 0, stream>>>(W2, w2t, NH1, NH2);
  wtrans_k<<<dim3(NY / 32, NH2 / 32, NE), dim3(32, 8), 0, stream>>>(W3, w3t, NH2, NY);

  gemm_k<64, ND, NH1, true, false><<<dim3(NH1 / 64, MAXT), 256, 0, stream>>>(
      hs, w1t, b1, meta, perm, a1s, (float*)nullptr);
  gemm_k<64, NH1, NH2, true, false><<<dim3(NH2 / 64, MAXT), 256, 0, stream>>>(
      a1s, w2t, b2, meta, perm, a2s, (float*)nullptr);
  gemm_k<64, NH2, NY, false, true><<<dim3(NY / 64, MAXT), 256, 0, stream>>>(
      a2s, w3t, b3, meta, perm, (unsigned short*)nullptr, out);
}

// Round 3
// 151.875 us; speedup vs baseline: 1.6283x; 1.0075x over previous
//
#include <hip/hip_runtime.h>
#include <stdint.h>

#define NE 8
#define ND 512
#define NH1 512
#define NH2 256
#define NY 256
#define NB 8192
#define BM 128
#define BK 32
#define MAXT (NB/BM + NE - 1)   /* 71 */
#define PADROWS (NB + BM)       /* 8320 */

typedef float f32x4 __attribute__((ext_vector_type(4)));
typedef __bf16 bf16x8 __attribute__((ext_vector_type(8)));
typedef unsigned short u16x8 __attribute__((ext_vector_type(8)));

__device__ __forceinline__ unsigned short f2bf(float f) {
  unsigned int u = __float_as_uint(f);
  u += 0x7fffu + ((u >> 16) & 1u);   // round-to-nearest-even
  return (unsigned short)(u >> 16);
}

__device__ __forceinline__ void async_cp16(const void* g, void* l) {
  __builtin_amdgcn_global_load_lds((const __attribute__((address_space(1))) void*)g,
                                   (__attribute__((address_space(3))) void*)l,
                                   16, 0, 0);
}

__device__ __forceinline__ int clampe(int g) {
  return g < 0 ? 0 : (g > NE - 1 ? NE - 1 : g);
}

// meta (ints): [0..7] counts, [8..15] offs, [24] ntiles, [32..127] tile table,
//              [128..383] blockhist[b][e], [512..767] base[b][e]

__global__ void hist_rank_k(const int* __restrict__ gate, int* __restrict__ meta,
                            int* __restrict__ rank) {
  __shared__ int lc[NE];
  int tid = threadIdx.x;
  if (tid < NE) lc[tid] = 0;
  __syncthreads();
  int row = blockIdx.x * 256 + tid;
  int g = clampe(gate[row]);
  rank[row] = atomicAdd(&lc[g], 1);
  __syncthreads();
  if (tid < NE) meta[128 + blockIdx.x * NE + tid] = lc[tid];
}

__global__ void scan_k(int* __restrict__ meta) {
  __shared__ int hist[256];
  __shared__ int basel[256];
  __shared__ int cnt[NE];
  int tid = threadIdx.x;
  hist[tid] = meta[128 + tid];            // [b][e] layout: b*8+e
  __syncthreads();
  if (tid < NE) {
    int run = 0;
    for (int b = 0; b < 32; b++) {
      basel[b * NE + tid] = run;
      run += hist[b * NE + tid];
    }
    cnt[tid] = run;
  }
  __syncthreads();
  __shared__ int offs[NE];
  if (tid == 0) {
    int off = 0, t = 0;
    for (int e = 0; e < NE; e++) {
      int c = cnt[e];
      meta[e] = c;
      meta[8 + e] = off;
      offs[e] = off;
      int ntl = (c + BM - 1) / BM;
      for (int i = 0; i < ntl; i++) meta[32 + t++] = (e << 16) | i;
      off += c;
    }
    meta[24] = t;
  }
  __syncthreads();
  meta[512 + tid] = offs[tid & (NE - 1)] + basel[tid];
}

// wave per row: slot = base[row>>8][g] + rank; gather h row fp32 -> bf16 sorted
__global__ void copy_k(const float* __restrict__ h, const int* __restrict__ gate,
                       const int* __restrict__ rank, const int* __restrict__ meta,
                       int* __restrict__ perm, unsigned short* __restrict__ hs) {
  int row  = blockIdx.x * 4 + (threadIdx.x >> 6);
  int lane = threadIdx.x & 63;
  int g = clampe(gate[row]);
  int slot = meta[512 + (row >> 8) * NE + g] + rank[row];
  if (lane == 0) perm[slot] = row;
  const float4* src = (const float4*)(h + (size_t)row * ND) + lane * 2;
  float4 v0 = src[0], v1 = src[1];
  union { u16x8 v; unsigned short u[8]; } pk;
  pk.u[0] = f2bf(v0.x); pk.u[1] = f2bf(v0.y); pk.u[2] = f2bf(v0.z); pk.u[3] = f2bf(v0.w);
  pk.u[4] = f2bf(v1.x); pk.u[5] = f2bf(v1.y); pk.u[6] = f2bf(v1.z); pk.u[7] = f2bf(v1.w);
  *(u16x8*)(hs + (size_t)slot * ND + lane * 8) = pk.v;
}

// All three W [G][K][N] fp32 -> Wt [G][N][K] bf16 in ONE launch (LDS-tiled transpose)
#define W1T (NE * (ND/32) * (NH1/32))   /* 2048 */
#define W2T (NE * (NH1/32) * (NH2/32))  /* 1024 */
#define W3T (NE * (NH2/32) * (NY/32))   /* 512  */
__global__ void wtrans_all_k(const float* __restrict__ W1, const float* __restrict__ W2,
                             const float* __restrict__ W3,
                             unsigned short* __restrict__ w1t, unsigned short* __restrict__ w2t,
                             unsigned short* __restrict__ w3t) {
  __shared__ float t[32][33];
  int b = blockIdx.x;
  const float* src; unsigned short* dst; int K, N, idx;
  if (b < W1T)            { src = W1; dst = w1t; K = ND;  N = NH1; idx = b; }
  else if (b < W1T + W2T) { src = W2; dst = w2t; K = NH1; N = NH2; idx = b - W1T; }
  else                    { src = W3; dst = w3t; K = NH2; N = NY;  idx = b - W1T - W2T; }
  int ntn = N >> 5, ntk = K >> 5;
  int n0 = (idx % ntn) * 32;
  int k0 = ((idx / ntn) % ntk) * 32;
  int g  = idx / (ntn * ntk);
  int tx = threadIdx.x, ty = threadIdx.y;
  src += (size_t)g * K * N;
  #pragma unroll
  for (int r = 0; r < 32; r += 8)
    t[ty + r][tx] = src[(size_t)(k0 + ty + r) * N + n0 + tx];
  __syncthreads();
  dst += (size_t)g * N * K;
  #pragma unroll
  for (int r = 0; r < 32; r += 8)
    dst[(size_t)(n0 + ty + r) * K + k0 + tx] = f2bf(t[tx][ty + r]);
}

// Grouped GEMM, m97 config: BM=128, BN=128, BK=32; 4 waves 2x2, wave tile 64x64.
// 16 MFMA : 8 ds_read_b128 per wave per k-iter.
template<int K, int N, bool LEAKY, bool SCATTER>
__global__ __launch_bounds__(256)
void gemm_k(const unsigned short* __restrict__ A,
            const unsigned short* __restrict__ Bt,
            const float* __restrict__ bias,
            const int* __restrict__ meta,
            const int* __restrict__ perm,
            unsigned short* __restrict__ Obf,
            float* __restrict__ Ofp)
{
  constexpr int BN = 128;
  constexpr int CA = BM * BK * 2 / 1024;   // 8 chunks of 1024B
  constexpr int CB = BN * BK * 2 / 1024;   // 8
  constexpr int CT = CA + CB;              // 16 -> 4 per wave

  __shared__ unsigned short As[BM * BK];
  __shared__ unsigned short Bs[BN * BK];

  if ((int)blockIdx.y >= meta[24]) return;
  int ent  = meta[32 + blockIdx.y];
  int e    = ent >> 16;
  int trow = ent & 0xffff;
  int cnt  = meta[e];
  int off  = meta[8 + e];
  int row0 = trow * BM;

  const unsigned short* Ae = A + (size_t)(off + row0) * K;
  const unsigned short* Be = Bt + ((size_t)e * N + (size_t)blockIdx.x * BN) * K;

  int tid  = threadIdx.x;
  int wave = tid >> 6, lane = tid & 63;
  int wx = wave & 1, wy = wave >> 1;
  int lm = lane & 15, quad = lane >> 4;
  int srow = lane >> 2;          // row within 16-row staging chunk
  int scol = (lane & 3) * 8;     // bf16-element offset within row

  f32x4 acc[4][4];
  f32x4 zero = {0.f, 0.f, 0.f, 0.f};
  #pragma unroll
  for (int mi = 0; mi < 4; mi++)
    #pragma unroll
    for (int ni = 0; ni < 4; ni++)
      acc[mi][ni] = zero;

  for (int k0 = 0; k0 < K; k0 += BK) {
    #pragma unroll
    for (int i = 0; i < 4; i++) {
      int c = wave + i * 4;
      if (c < CA)
        async_cp16(Ae + (size_t)(c * 16 + srow) * K + k0 + scol, &As[c * 512]);
      else
        async_cp16(Be + (size_t)((c - CA) * 16 + srow) * K + k0 + scol, &Bs[(c - CA) * 512]);
    }
    __syncthreads();
    bf16x8 af[4], bfr[4];
    #pragma unroll
    for (int mi = 0; mi < 4; mi++)
      af[mi] = *reinterpret_cast<const bf16x8*>(&As[(wy * 64 + mi * 16 + lm) * BK + quad * 8]);
    #pragma unroll
    for (int ni = 0; ni < 4; ni++)
      bfr[ni] = *reinterpret_cast<const bf16x8*>(&Bs[(wx * 64 + ni * 16 + lm) * BK + quad * 8]);
    #pragma unroll
    for (int mi = 0; mi < 4; mi++)
      #pragma unroll
      for (int ni = 0; ni < 4; ni++)
        acc[mi][ni] = __builtin_amdgcn_mfma_f32_16x16x32_bf16(af[mi], bfr[ni], acc[mi][ni], 0, 0, 0);
    __syncthreads();
  }

  #pragma unroll
  for (int mi = 0; mi < 4; mi++) {
    #pragma unroll
    for (int ni = 0; ni < 4; ni++) {
      int col = blockIdx.x * BN + wx * 64 + ni * 16 + lm;
      float bv = bias[e * N + col];
      #pragma unroll
      for (int r = 0; r < 4; r++) {
        int ml   = wy * 64 + mi * 16 + quad * 4 + r;  // C/D: row=quad*4+reg, col=lane&15
        int grow = row0 + ml;
        if (grow < cnt) {
          float v = acc[mi][ni][r] + bv;
          if (LEAKY) v = (v > 0.f) ? v : 0.2f * v;
          int s = off + grow;
          if (SCATTER)
            Ofp[(size_t)perm[s] * N + col] = v;
          else
            Obf[(size_t)s * N + col] = f2bf(v);
        }
      }
    }
  }
}

extern "C" void kernel_launch(void* const* d_in, const int* in_sizes, int n_in,
                              void* d_out, int out_size, void* d_ws, size_t ws_size,
                              hipStream_t stream) {
  (void)in_sizes; (void)n_in; (void)out_size; (void)ws_size;
  const float* h  = (const float*)d_in[0];
  const int* gate = (const int*)d_in[1];
  const float* W1 = (const float*)d_in[2];
  const float* b1 = (const float*)d_in[3];
  const float* W2 = (const float*)d_in[4];
  const float* b2 = (const float*)d_in[5];
  const float* W3 = (const float*)d_in[6];
  const float* b3 = (const float*)d_in[7];
  float* out = (float*)d_out;

  char* ws = (char*)d_ws;
  int* meta = (int*)ws;                               // 4096 B
  int* rank = (int*)(ws + 4096);                      // 32 KB
  int* perm = (int*)(ws + 4096 + 32768);              // 32 KB
  unsigned short* hs  = (unsigned short*)(ws + 4096 + 65536);
  unsigned short* a1s = hs  + (size_t)PADROWS * ND;
  unsigned short* a2s = a1s + (size_t)PADROWS * NH1;
  unsigned short* w1t = a2s + (size_t)PADROWS * NH2;
  unsigned short* w2t = w1t + (size_t)NE * ND * NH1;
  unsigned short* w3t = w2t + (size_t)NE * NH1 * NH2;
  // total ~28.8 MB of d_ws

  hist_rank_k<<<NB / 256, 256, 0, stream>>>(gate, meta, rank);
  scan_k<<<1, 256, 0, stream>>>(meta);
  copy_k<<<NB / 4, 256, 0, stream>>>(h, gate, rank, meta, perm, hs);
  wtrans_all_k<<<W1T + W2T + W3T, dim3(32, 8), 0, stream>>>(W1, W2, W3, w1t, w2t, w3t);

  gemm_k<ND, NH1, true, false><<<dim3(NH1 / 128, MAXT), 256, 0, stream>>>(
      hs, w1t, b1, meta, perm, a1s, (float*)nullptr);
  gemm_k<NH1, NH2, true, false><<<dim3(NH2 / 128, MAXT), 256, 0, stream>>>(
      a1s, w2t, b2, meta, perm, a2s, (float*)nullptr);
  gemm_k<NH2, NY, false, true><<<dim3(NY / 128, MAXT), 256, 0, stream>>>(
      a2s, w3t, b3, meta, perm, (unsigned short*)nullptr, out);
}